// Round 14
// baseline (696.270 us; speedup 1.0000x reference)
//
#include <hip/hip_runtime.h>

#define NB 16
#define NL 1024
#define ND 64
#define NW 20
#define CH 16                   // l's per block (rolling)
#define THR 0.3f
#define REP_STORE 4
#define REP_COMP 12

typedef float f32x4 __attribute__((ext_vector_type(4)));

// ======================= DIAGNOSTIC ROUND (R14) =======================
// Six consecutive nulls at ~62us: occupancy/NT/contiguity/VALU-cut all no-op.
// Ablate empirically: measure store-path and compute-path in isolation.
// Dispatch order: store_only (garbage->d_out, x4 reps), compute_only (no
// stores, asm-kept, x12 reps), then the real kernel overwrites d_out
// correctly. Per-dispatch rocprof rows give the breakdown.

// --- (1) bare store pattern: R12 addresses, trivial values ---
__global__ void store_only_kernel(const float* __restrict__ x,
                                  float* __restrict__ out)
{
    const int blk = blockIdx.x;            // 0..1023
    const int b   = blk >> 6;
    const int l0  = (blk & 63) * CH;
    const int t   = threadIdx.x;
    const int q   = t >> 6;
    const int g   = (t >> 4) & 3;
    const int tc  = t & 15;
    const int r0  = (q << 4) + g;
    const int e0  = tc << 2;

    f32x4 v = *(const f32x4*)&x[(size_t)(blk * 256 + t) * 4];
    float* obase = out + ((size_t)b * NL + l0) * (ND * ND);

    for (int r = 0; r < REP_STORE; ++r) {
        for (int s = 0; s < CH; ++s) {
            float* ob = obase + (size_t)s * (ND * ND);
            #pragma unroll
            for (int i = 0; i < 4; ++i) {
                f32x4 o = v;
                o.x += (float)(s + i + r);
                __builtin_nontemporal_store(o, (f32x4*)&ob[(r0 + 4 * i) * ND + e0]);
            }
        }
    }
}

// --- (2) bare compute: full R13 pipeline, stores -> asm keeps ---
__global__ void compute_only_kernel(const float* __restrict__ x)
{
    const int blk = blockIdx.x;
    const int b   = blk >> 6;
    const int l0  = (blk & 63) * CH;
    const int t   = threadIdx.x;

    const int NROW = NW - 1 + CH;
    __shared__ float win[NW - 1 + CH][ND];

    const float* xb = x + ((size_t)b * NL) * ND;

    #pragma unroll
    for (int i = 0; i < 3; ++i) {
        int s = t + i * 256;
        if (s < NROW * 16) {
            int w    = s >> 4;
            int c4   = (s & 15) << 2;
            int lsrc = l0 - (NW - 1) + w;
            f32x4 v = {0.f, 0.f, 0.f, 0.f};
            if (lsrc >= 0) v = *(const f32x4*)&xb[(size_t)lsrc * ND + c4];
            *(f32x4*)&win[w][c4] = v;
        }
    }
    __syncthreads();

    const int q  = t >> 6;
    const int g  = (t >> 4) & 3;
    const int tc = t & 15;
    const int r0 = (q << 4) + g;
    const int e0 = tc << 2;

    const float invW  = 1.0f / NW;
    const float EPS19 = 19e-8f;

    for (int r = 0; r < REP_COMP; ++r) {
        float pert = (float)r * 1e-30f;    // defeat cross-rep CSE
        float acc[4][4] = {};
        float rs[4] = {}, rq[4] = {};
        float cs[4] = {}, cq[4] = {};

        #pragma unroll
        for (int w = 0; w < NW; ++w) {
            float ar[4];
            ar[0] = win[w][r0];
            ar[1] = win[w][r0 + 4];
            ar[2] = win[w][r0 + 8];
            ar[3] = win[w][r0 + 12];
            f32x4 b0 = *(const f32x4*)&win[w][e0];
            float br[4] = {b0.x, b0.y, b0.z, b0.w};
            #pragma unroll
            for (int i = 0; i < 4; ++i) {
                rs[i] += ar[i];
                rq[i]  = fmaf(ar[i], ar[i], rq[i]);
                #pragma unroll
                for (int j = 0; j < 4; ++j)
                    acc[i][j] = fmaf(ar[i], br[j], acc[i][j]);
            }
            #pragma unroll
            for (int j = 0; j < 4; ++j) {
                cs[j] += br[j];
                cq[j]  = fmaf(br[j], br[j], cq[j]);
            }
        }
        #pragma unroll
        for (int i = 0; i < 4; ++i) {
            rs[i] += pert; rq[i] += pert;
            cs[i] += pert; cq[i] += pert;
            #pragma unroll
            for (int j = 0; j < 4; ++j) acc[i][j] += pert;
        }

        for (int s = 0; s < CH; ++s) {
            float sdu[4], seu[4], mc[4];
            #pragma unroll
            for (int i = 0; i < 4; ++i) {
                float qv = fmaf(-rs[i] * invW, rs[i], rq[i]);
                sdu[i] = sqrtf(qv);
            }
            #pragma unroll
            for (int j = 0; j < 4; ++j) {
                mc[j] = cs[j] * invW;
                float qv = fmaf(-cs[j], mc[j], cq[j]);
                seu[j] = sqrtf(qv);
            }
            #pragma unroll
            for (int i = 0; i < 4; ++i) {
                f32x4 o;
                float cv;
                cv = fmaf(-rs[i], mc[0], acc[i][0]);
                o.x = fmaxf(fabsf(__fdividef(cv, fmaf(sdu[i], seu[0], EPS19))) - THR, 0.0f);
                cv = fmaf(-rs[i], mc[1], acc[i][1]);
                o.y = fmaxf(fabsf(__fdividef(cv, fmaf(sdu[i], seu[1], EPS19))) - THR, 0.0f);
                cv = fmaf(-rs[i], mc[2], acc[i][2]);
                o.z = fmaxf(fabsf(__fdividef(cv, fmaf(sdu[i], seu[2], EPS19))) - THR, 0.0f);
                cv = fmaf(-rs[i], mc[3], acc[i][3]);
                o.w = fmaxf(fabsf(__fdividef(cv, fmaf(sdu[i], seu[3], EPS19))) - THR, 0.0f);
                asm volatile("" :: "v"(o.x), "v"(o.y), "v"(o.z), "v"(o.w));
            }

            if (s < CH - 1) {
                float an[4], ao[4];
                an[0] = win[s + NW][r0];
                an[1] = win[s + NW][r0 + 4];
                an[2] = win[s + NW][r0 + 8];
                an[3] = win[s + NW][r0 + 12];
                ao[0] = win[s][r0];
                ao[1] = win[s][r0 + 4];
                ao[2] = win[s][r0 + 8];
                ao[3] = win[s][r0 + 12];
                f32x4 nb  = *(const f32x4*)&win[s + NW][e0];
                f32x4 obv = *(const f32x4*)&win[s][e0];
                float bn[4] = {nb.x, nb.y, nb.z, nb.w};
                float bo[4] = {obv.x, obv.y, obv.z, obv.w};
                #pragma unroll
                for (int i = 0; i < 4; ++i) {
                    rs[i] += an[i] - ao[i];
                    rq[i]  = fmaf(an[i], an[i], fmaf(-ao[i], ao[i], rq[i]));
                    #pragma unroll
                    for (int j = 0; j < 4; ++j)
                        acc[i][j] = fmaf(an[i], bn[j], fmaf(-ao[i], bo[j], acc[i][j]));
                }
                #pragma unroll
                for (int j = 0; j < 4; ++j) {
                    cs[j] += bn[j] - bo[j];
                    cq[j]  = fmaf(bn[j], bn[j], fmaf(-bo[j], bo[j], cq[j]));
                }
            }
        }
    }
}

// --- (3) the real kernel (R13, unchanged) ---
__global__ void dyn_corr_kernel(
    const float* __restrict__ x, float* __restrict__ out)
{
    const int blk = blockIdx.x;
    const int b   = blk >> 6;
    const int l0  = (blk & 63) * CH;
    const int t   = threadIdx.x;

    const int NROW = NW - 1 + CH;
    __shared__ float win[NW - 1 + CH][ND];

    const float* xb = x + ((size_t)b * NL) * ND;

    #pragma unroll
    for (int i = 0; i < 3; ++i) {
        int s = t + i * 256;
        if (s < NROW * 16) {
            int w    = s >> 4;
            int c4   = (s & 15) << 2;
            int lsrc = l0 - (NW - 1) + w;
            f32x4 v = {0.f, 0.f, 0.f, 0.f};
            if (lsrc >= 0) v = *(const f32x4*)&xb[(size_t)lsrc * ND + c4];
            *(f32x4*)&win[w][c4] = v;
        }
    }
    __syncthreads();

    const int q  = t >> 6;
    const int g  = (t >> 4) & 3;
    const int tc = t & 15;
    const int r0 = (q << 4) + g;
    const int e0 = tc << 2;

    float acc[4][4] = {};
    float rs[4] = {}, rq[4] = {};
    float cs[4] = {}, cq[4] = {};

    #pragma unroll
    for (int w = 0; w < NW; ++w) {
        float ar[4];
        ar[0] = win[w][r0];
        ar[1] = win[w][r0 + 4];
        ar[2] = win[w][r0 + 8];
        ar[3] = win[w][r0 + 12];
        f32x4 b0 = *(const f32x4*)&win[w][e0];
        float br[4] = {b0.x, b0.y, b0.z, b0.w};
        #pragma unroll
        for (int i = 0; i < 4; ++i) {
            rs[i] += ar[i];
            rq[i]  = fmaf(ar[i], ar[i], rq[i]);
            #pragma unroll
            for (int j = 0; j < 4; ++j)
                acc[i][j] = fmaf(ar[i], br[j], acc[i][j]);
        }
        #pragma unroll
        for (int j = 0; j < 4; ++j) {
            cs[j] += br[j];
            cq[j]  = fmaf(br[j], br[j], cq[j]);
        }
    }

    const float invW  = 1.0f / NW;
    const float EPS19 = 19e-8f;
    float* obase = out + ((size_t)b * NL + l0) * (ND * ND);

    #pragma unroll 2
    for (int s = 0; s < CH; ++s) {
        float sdu[4], seu[4], mc[4];
        #pragma unroll
        for (int i = 0; i < 4; ++i) {
            float qv = fmaf(-rs[i] * invW, rs[i], rq[i]);
            sdu[i] = sqrtf(qv);
        }
        #pragma unroll
        for (int j = 0; j < 4; ++j) {
            mc[j] = cs[j] * invW;
            float qv = fmaf(-cs[j], mc[j], cq[j]);
            seu[j] = sqrtf(qv);
        }
        float* ob = obase + (size_t)s * (ND * ND);
        #pragma unroll
        for (int i = 0; i < 4; ++i) {
            f32x4 o;
            float cv;
            cv = fmaf(-rs[i], mc[0], acc[i][0]);
            o.x = fmaxf(fabsf(__fdividef(cv, fmaf(sdu[i], seu[0], EPS19))) - THR, 0.0f);
            cv = fmaf(-rs[i], mc[1], acc[i][1]);
            o.y = fmaxf(fabsf(__fdividef(cv, fmaf(sdu[i], seu[1], EPS19))) - THR, 0.0f);
            cv = fmaf(-rs[i], mc[2], acc[i][2]);
            o.z = fmaxf(fabsf(__fdividef(cv, fmaf(sdu[i], seu[2], EPS19))) - THR, 0.0f);
            cv = fmaf(-rs[i], mc[3], acc[i][3]);
            o.w = fmaxf(fabsf(__fdividef(cv, fmaf(sdu[i], seu[3], EPS19))) - THR, 0.0f);
            __builtin_nontemporal_store(o, (f32x4*)&ob[(r0 + 4 * i) * ND + e0]);
        }

        if (s < CH - 1) {
            float an[4], ao[4];
            an[0] = win[s + NW][r0];
            an[1] = win[s + NW][r0 + 4];
            an[2] = win[s + NW][r0 + 8];
            an[3] = win[s + NW][r0 + 12];
            ao[0] = win[s][r0];
            ao[1] = win[s][r0 + 4];
            ao[2] = win[s][r0 + 8];
            ao[3] = win[s][r0 + 12];
            f32x4 nb  = *(const f32x4*)&win[s + NW][e0];
            f32x4 obv = *(const f32x4*)&win[s][e0];
            float bn[4] = {nb.x, nb.y, nb.z, nb.w};
            float bo[4] = {obv.x, obv.y, obv.z, obv.w};
            #pragma unroll
            for (int i = 0; i < 4; ++i) {
                rs[i] += an[i] - ao[i];
                rq[i]  = fmaf(an[i], an[i], fmaf(-ao[i], ao[i], rq[i]));
                #pragma unroll
                for (int j = 0; j < 4; ++j)
                    acc[i][j] = fmaf(an[i], bn[j], fmaf(-ao[i], bo[j], acc[i][j]));
            }
            #pragma unroll
            for (int j = 0; j < 4; ++j) {
                cs[j] += bn[j] - bo[j];
                cq[j]  = fmaf(bn[j], bn[j], fmaf(-bo[j], bo[j], cq[j]));
            }
        }
    }
}

extern "C" void kernel_launch(void* const* d_in, const int* in_sizes, int n_in,
                              void* d_out, int out_size, void* d_ws, size_t ws_size,
                              hipStream_t stream) {
    const float* x = (const float*)d_in[0];
    float* out = (float*)d_out;
    dim3 grid(NB * (NL / CH));
    dim3 block(256);
    // diagnostics first (store_only scribbles on d_out; real kernel last
    // overwrites with correct values -> validation unaffected)
    hipLaunchKernelGGL(store_only_kernel, grid, block, 0, stream, x, out);
    hipLaunchKernelGGL(compute_only_kernel, grid, block, 0, stream, x);
    hipLaunchKernelGGL(dyn_corr_kernel, grid, block, 0, stream, x, out);
}

// Round 15
// 56.302 us; speedup vs baseline: 12.3667x; 12.3667x over previous
//
#include <hip/hip_runtime.h>

#define NB 16
#define NL 1024
#define ND 64
#define NW 20
#define CH 16                   // l's per block (rolling)
#define THR 0.3f

typedef float f32x4 __attribute__((ext_vector_type(4)));

// Rolling-window, 256 threads per (b, 16-l chunk). Strided row ownership
// (R12): store instruction i covers 1KB contiguous per wave.
// R15: raw-instruction transcendentals. R14 ablation: compute-only = 57.5us
// at 97% VALUBusy (kernel is compute-bound; stores add ~4.5us). The 4x gap
// vs hand-counted ops = sqrtf's denormal-fixup libcall + __fdividef's
// div_scale/div_fmas lowering. v_sqrt_f32 / v_rcp_f32 via builtins are 1
// inst each; |cv| folds into the fma as a src modifier.
// EPILOGUE eps semantics EXACT: den = sdu*seu + 19e-8 (x19-rescaled ref eps;
// R8's absmax-0.7 bug was eps REMOVAL — rescale is algebraically identical).
// RULES: no runtime indexing into register arrays (R5: scratch demotion, 6x);
// no __launch_bounds__ occupancy hints (R3/R4: forced spill).
__global__ void dyn_corr_kernel(
    const float* __restrict__ x, float* __restrict__ out)
{
    const int blk = blockIdx.x;            // 0..1023
    const int b   = blk >> 6;              // 64 chunks per batch
    const int l0  = (blk & 63) * CH;
    const int t   = threadIdx.x;           // 0..255

    const int NROW = NW - 1 + CH;          // 35 staged rows: l0-19 .. l0+15
    __shared__ float win[NW - 1 + CH][ND]; // 8960 B, raw (uncentered)

    const float* xb = x + ((size_t)b * NL) * ND;

    // --- stage 35 rows (zeros for l<0), f32x4, coalesced ---
    #pragma unroll
    for (int i = 0; i < 3; ++i) {
        int s = t + i * 256;               // valid < 560
        if (s < NROW * 16) {
            int w    = s >> 4;
            int c4   = (s & 15) << 2;
            int lsrc = l0 - (NW - 1) + w;
            f32x4 v = {0.f, 0.f, 0.f, 0.f};
            if (lsrc >= 0) v = *(const f32x4*)&xb[(size_t)lsrc * ND + c4];
            *(f32x4*)&win[w][c4] = v;
        }
    }
    __syncthreads();                       // win read-only from here on

    const int q  = t >> 6;                 // wave 0..3 -> rows 16q..16q+15
    const int g  = (t >> 4) & 3;           // row-group within wave
    const int tc = t & 15;                 // col group
    const int r0 = (q << 4) + g;           // row(i) = r0 + 4*i
    const int e0 = tc << 2;                // cols e0..e0+3

    float acc[4][4] = {};                  // raw Gram tile (row i, col j)
    float rs[4] = {}, rq[4] = {};          // row sum / sumsq
    float cs[4] = {}, cq[4] = {};          // col sum / sumsq

    // --- init: full first window, LDS rows 0..19 (= l0-19..l0) ---
    #pragma unroll
    for (int w = 0; w < NW; ++w) {
        float ar[4];
        ar[0] = win[w][r0];
        ar[1] = win[w][r0 + 4];
        ar[2] = win[w][r0 + 8];
        ar[3] = win[w][r0 + 12];
        f32x4 b0 = *(const f32x4*)&win[w][e0];
        float br[4] = {b0.x, b0.y, b0.z, b0.w};
        #pragma unroll
        for (int i = 0; i < 4; ++i) {
            rs[i] += ar[i];
            rq[i]  = fmaf(ar[i], ar[i], rq[i]);
            #pragma unroll
            for (int j = 0; j < 4; ++j)
                acc[i][j] = fmaf(ar[i], br[j], acc[i][j]);
        }
        #pragma unroll
        for (int j = 0; j < 4; ++j) {
            cs[j] += br[j];
            cq[j]  = fmaf(br[j], br[j], cq[j]);
        }
    }

    const float invW  = 1.0f / NW;
    const float EPS19 = 19e-8f;            // 19 * 1e-8 (rescaled ref eps)
    float* obase = out + ((size_t)b * NL + l0) * (ND * ND);

    #pragma unroll 2
    for (int s = 0; s < CH; ++s) {
        // --- epilogue for l = l0 + s (x19-rescaled, eps semantics exact) ---
        float sdu[4], seu[4], mc[4];
        #pragma unroll
        for (int i = 0; i < 4; ++i) {
            float qv = fmaf(-rs[i] * invW, rs[i], rq[i]);
            sdu[i] = __builtin_amdgcn_sqrtf(qv);   // v_sqrt_f32, 1 inst
        }
        #pragma unroll
        for (int j = 0; j < 4; ++j) {
            mc[j] = cs[j] * invW;
            float qv = fmaf(-cs[j], mc[j], cq[j]);
            seu[j] = __builtin_amdgcn_sqrtf(qv);
        }
        float* ob = obase + (size_t)s * (ND * ND);
        #pragma unroll
        for (int i = 0; i < 4; ++i) {
            f32x4 o;
            float cv, r;
            cv = fmaf(-rs[i], mc[0], acc[i][0]);
            r  = __builtin_amdgcn_rcpf(fmaf(sdu[i], seu[0], EPS19)); // v_rcp_f32
            o.x = fmaxf(fmaf(fabsf(cv), r, -THR), 0.0f);
            cv = fmaf(-rs[i], mc[1], acc[i][1]);
            r  = __builtin_amdgcn_rcpf(fmaf(sdu[i], seu[1], EPS19));
            o.y = fmaxf(fmaf(fabsf(cv), r, -THR), 0.0f);
            cv = fmaf(-rs[i], mc[2], acc[i][2]);
            r  = __builtin_amdgcn_rcpf(fmaf(sdu[i], seu[2], EPS19));
            o.z = fmaxf(fmaf(fabsf(cv), r, -THR), 0.0f);
            cv = fmaf(-rs[i], mc[3], acc[i][3]);
            r  = __builtin_amdgcn_rcpf(fmaf(sdu[i], seu[3], EPS19));
            o.w = fmaxf(fmaf(fabsf(cv), r, -THR), 0.0f);
            // instr i: rows 16q+4i+{0..3} x 256B -> 1KB contiguous per wave
            __builtin_nontemporal_store(o, (f32x4*)&ob[(r0 + 4 * i) * ND + e0]);
        }

        // --- rolling update l -> l+1: add LDS row s+20, remove row s ---
        if (s < CH - 1) {
            float an[4], ao[4];
            an[0] = win[s + NW][r0];
            an[1] = win[s + NW][r0 + 4];
            an[2] = win[s + NW][r0 + 8];
            an[3] = win[s + NW][r0 + 12];
            ao[0] = win[s][r0];
            ao[1] = win[s][r0 + 4];
            ao[2] = win[s][r0 + 8];
            ao[3] = win[s][r0 + 12];
            f32x4 nb  = *(const f32x4*)&win[s + NW][e0];
            f32x4 obv = *(const f32x4*)&win[s][e0];
            float bn[4] = {nb.x, nb.y, nb.z, nb.w};
            float bo[4] = {obv.x, obv.y, obv.z, obv.w};
            #pragma unroll
            for (int i = 0; i < 4; ++i) {
                rs[i] += an[i] - ao[i];
                rq[i]  = fmaf(an[i], an[i], fmaf(-ao[i], ao[i], rq[i]));
                #pragma unroll
                for (int j = 0; j < 4; ++j)
                    acc[i][j] = fmaf(an[i], bn[j], fmaf(-ao[i], bo[j], acc[i][j]));
            }
            #pragma unroll
            for (int j = 0; j < 4; ++j) {
                cs[j] += bn[j] - bo[j];
                cq[j]  = fmaf(bn[j], bn[j], fmaf(-bo[j], bo[j], cq[j]));
            }
        }
    }
}

extern "C" void kernel_launch(void* const* d_in, const int* in_sizes, int n_in,
                              void* d_out, int out_size, void* d_ws, size_t ws_size,
                              hipStream_t stream) {
    const float* x = (const float*)d_in[0];
    float* out = (float*)d_out;
    dim3 grid(NB * (NL / CH));
    dim3 block(256);
    hipLaunchKernelGGL(dyn_corr_kernel, grid, block, 0, stream, x, out);
}